// Round 1
// baseline (351.485 us; speedup 1.0000x reference)
//
#include <hip/hip_runtime.h>

// Equivariant linear: segments (u,i) = (64,1),(32,3),(16,5); in==out, 240 cols.
// o[n,v,i] = (1/sqrt(u)) * sum_u x[n,u,i] * w[u,v], per segment.
// Memory-bound: 384 MB HBM traffic, target ~61 us @ 6.3 TB/s.

#define TILE 32
#define BLOCK 256

__global__ __launch_bounds__(BLOCK, 3) void eqlin_kernel(
    const float* __restrict__ x, const float* __restrict__ w,
    float* __restrict__ out, int nrows)
{
    __shared__ __align__(16) float xs[TILE * 240];   // 30720 B, row-major, stride 240
    __shared__ __align__(16) float ws[5376];         // 21504 B

    const int tid = threadIdx.x;
    const long long row0 = (long long)blockIdx.x * TILE;

    // ---- stage weights (1344 float4) ----
    {
        const float4* wg = (const float4*)w;
        float4* wl = (float4*)ws;
        #pragma unroll 2
        for (int idx = tid; idx < 1344; idx += BLOCK) wl[idx] = wg[idx];
    }
    // ---- stage x tile (1920 float4), fully coalesced ----
    {
        const float4* xg = (const float4*)(x + row0 * 240);
        float4* xl = (float4*)xs;
        #pragma unroll 2
        for (int idx = tid; idx < 1920; idx += BLOCK) xl[idx] = xg[idx];
    }
    __syncthreads();

    const int lane = tid & 63;
    const int wvid = tid >> 6;   // wave 0..3
    const int rb = wvid * 8;     // this wave's 8 rows; no cross-wave LDS sharing below

    // ================= segment 0: u=v=64, i=1, cols [0,64) =================
    {
        const int v = lane;                   // lane-consecutive weight reads
        float acc[8];
        #pragma unroll
        for (int r = 0; r < 8; ++r) acc[r] = 0.f;
        #pragma unroll 4
        for (int k = 0; k < 16; ++k) {        // u in groups of 4
            const float w0 = ws[(4*k+0)*64 + v];
            const float w1 = ws[(4*k+1)*64 + v];
            const float w2 = ws[(4*k+2)*64 + v];
            const float w3 = ws[(4*k+3)*64 + v];
            #pragma unroll
            for (int r = 0; r < 8; ++r) {
                const float4 xq = *(const float4*)&xs[(rb + r)*240 + 4*k]; // wave-broadcast
                acc[r] += xq.x*w0 + xq.y*w1 + xq.z*w2 + xq.w*w3;
            }
        }
        // in-place writeback (all reads of this region are done; wave-private rows)
        #pragma unroll
        for (int r = 0; r < 8; ++r) xs[(rb + r)*240 + v] = acc[r] * 0.125f;
    }

    // ================= segment 1: u=v=32, i=3, cols [64,160) =================
    {
        const int v  = lane & 31;
        const int h  = lane >> 5;             // half-wave -> row subset
        const int r0 = rb + h * 4;            // 4 rows per lane
        float acc[4][3];
        #pragma unroll
        for (int r = 0; r < 4; ++r)
            #pragma unroll
            for (int i = 0; i < 3; ++i) acc[r][i] = 0.f;
        #pragma unroll 4
        for (int k = 0; k < 8; ++k) {         // u in groups of 4 -> 12 contiguous floats
            const float w0 = ws[4096 + (4*k+0)*32 + v];
            const float w1 = ws[4096 + (4*k+1)*32 + v];
            const float w2 = ws[4096 + (4*k+2)*32 + v];
            const float w3 = ws[4096 + (4*k+3)*32 + v];
            #pragma unroll
            for (int r = 0; r < 4; ++r) {
                const float* xr = &xs[(r0 + r)*240 + 64 + 12*k];
                const float4 a = *(const float4*)(xr);       // (du,i): 00 01 02 10
                const float4 b = *(const float4*)(xr + 4);   // 11 12 20 21
                const float4 c = *(const float4*)(xr + 8);   // 22 30 31 32
                acc[r][0] += a.x*w0 + a.w*w1 + b.z*w2 + c.y*w3;
                acc[r][1] += a.y*w0 + b.x*w1 + b.w*w2 + c.z*w3;
                acc[r][2] += a.z*w0 + b.y*w1 + c.x*w2 + c.w*w3;
            }
        }
        const float s1 = 0.17677669529663687f;   // 1/sqrt(32)
        #pragma unroll
        for (int r = 0; r < 4; ++r)
            #pragma unroll
            for (int i = 0; i < 3; ++i)
                xs[(r0 + r)*240 + 64 + v*3 + i] = acc[r][i] * s1;
    }

    // ================= segment 2: u=v=16, i=5, cols [160,240) =================
    {
        const int v  = lane & 15;
        const int q  = lane >> 4;             // quarter-wave -> row subset
        const int r0 = rb + q * 2;            // 2 rows per lane
        float acc[2][5];
        #pragma unroll
        for (int r = 0; r < 2; ++r)
            #pragma unroll
            for (int i = 0; i < 5; ++i) acc[r][i] = 0.f;
        #pragma unroll
        for (int k = 0; k < 4; ++k) {         // u in groups of 4 -> 20 contiguous floats
            const float w0 = ws[5120 + (4*k+0)*16 + v];
            const float w1 = ws[5120 + (4*k+1)*16 + v];
            const float w2 = ws[5120 + (4*k+2)*16 + v];
            const float w3 = ws[5120 + (4*k+3)*16 + v];
            #pragma unroll
            for (int r = 0; r < 2; ++r) {
                const float* xr = &xs[(r0 + r)*240 + 160 + 20*k];
                const float4 a = *(const float4*)(xr);       // idx 0..3
                const float4 b = *(const float4*)(xr + 4);   // 4..7
                const float4 c = *(const float4*)(xr + 8);   // 8..11
                const float4 d = *(const float4*)(xr + 12);  // 12..15
                const float4 e = *(const float4*)(xr + 16);  // 16..19
                acc[r][0] += a.x*w0 + b.y*w1 + c.z*w2 + d.w*w3;  // idx 0,5,10,15
                acc[r][1] += a.y*w0 + b.z*w1 + c.w*w2 + e.x*w3;  // 1,6,11,16
                acc[r][2] += a.z*w0 + b.w*w1 + d.x*w2 + e.y*w3;  // 2,7,12,17
                acc[r][3] += a.w*w0 + c.x*w1 + d.y*w2 + e.z*w3;  // 3,8,13,18
                acc[r][4] += b.x*w0 + c.y*w1 + d.z*w2 + e.w*w3;  // 4,9,14,19
            }
        }
        #pragma unroll
        for (int r = 0; r < 2; ++r)
            #pragma unroll
            for (int i = 0; i < 5; ++i)
                xs[(r0 + r)*240 + 160 + v*5 + i] = acc[r][i] * 0.25f;
    }

    __syncthreads();

    // ---- coalesced bulk store of the transformed tile ----
    {
        float4* og = (float4*)(out + row0 * 240);
        const float4* xl = (const float4*)xs;
        #pragma unroll 2
        for (int idx = tid; idx < 1920; idx += BLOCK) og[idx] = xl[idx];
    }
}

extern "C" void kernel_launch(void* const* d_in, const int* in_sizes, int n_in,
                              void* d_out, int out_size, void* d_ws, size_t ws_size,
                              hipStream_t stream) {
    const float* x = (const float*)d_in[0];
    const float* w = (const float*)d_in[1];
    float* out = (float*)d_out;
    const int nrows = in_sizes[0] / 240;          // 200000
    const int blocks = nrows / TILE;              // 6250 (exact)
    eqlin_kernel<<<blocks, BLOCK, 0, stream>>>(x, w, out, nrows);
}